// Round 8
// baseline (315.692 us; speedup 1.0000x reference)
//
#include <hip/hip_runtime.h>

#define NCLASS 100
#define TROWS 64       // rows per tile == threads per block (1 wave)
#define CHUNKS 25      // float4 chunks per row

typedef float fx4 __attribute__((ext_vector_type(4)));

// Double-buffered global_load_lds streaming (no VGPR staging, no barriers)
// + fused entropy epilogue: the LAST block to finish (device-scope done
// counter) reads the global histogram and writes the entropy scalar.
__global__ __launch_bounds__(64) void argmax_hist_entropy_kernel(
    const fx4* __restrict__ g4,
    unsigned int* __restrict__ counts,   // [NCLASS] zeroed by memset
    unsigned int* __restrict__ done,     // [1] zeroed by memset
    float* __restrict__ out,
    int nrows)
{
    __shared__ fx4 buf[2][CHUNKS * TROWS];   // 2 x 25600 B
    __shared__ unsigned int lhist[NCLASS];   // 400 B  -> 51.6 KB, 3 blocks/CU
    __shared__ unsigned int s_last;

    const int tid = threadIdx.x;
    #pragma unroll
    for (int i = tid; i < NCLASS; i += TROWS) lhist[i] = 0u;
    __syncthreads();

    const int ntiles = nrows / TROWS;        // 65536 exactly
    const int stride = gridDim.x;

    #define ISSUE_TILE(b_, tile_)                                               \
        {                                                                       \
            const fx4* src = g4 + (size_t)(tile_) * (CHUNKS * TROWS) + tid;     \
            _Pragma("unroll")                                                   \
            for (int i = 0; i < CHUNKS; ++i) {                                  \
                __builtin_amdgcn_global_load_lds(                               \
                    (const __attribute__((address_space(1))) void*)(src + i * TROWS), \
                    (__attribute__((address_space(3))) void*)(&buf[(b_)][i * TROWS]), \
                    16, 0, 0);                                                  \
            }                                                                   \
        }

    int tile = blockIdx.x;
    int b = 0;
    if (tile < ntiles) ISSUE_TILE(0, tile);

    while (tile < ntiles) {
        const int nxt = tile + stride;
        if (nxt < ntiles) {
            ISSUE_TILE(b ^ 1, nxt);
            // 50 outstanding; wait until <=25 -> buf[b]'s 25 have landed.
            asm volatile("s_waitcnt vmcnt(25)" ::: "memory");
        } else {
            asm volatile("s_waitcnt vmcnt(0)" ::: "memory");
        }
        __builtin_amdgcn_sched_barrier(0);   // keep reads below the wait

        // ---- row-scan: thread t reads row t (25 fx4) in column order ----
        const fx4* rp = &buf[b][tid * CHUNKS];   // row-major [64][100] floats
        float best = -__builtin_huge_valf();
        int bcol = 0;
        #pragma unroll
        for (int j = 0; j < CHUNKS; ++j) {
            const fx4 v = rp[j];
            if (v.x > best) { best = v.x; bcol = 4 * j + 0; }  // strict > => first max
            if (v.y > best) { best = v.y; bcol = 4 * j + 1; }
            if (v.z > best) { best = v.z; bcol = 4 * j + 2; }
            if (v.w > best) { best = v.w; bcol = 4 * j + 3; }
        }
        atomicAdd(&lhist[bcol], 1u);

        b ^= 1;
        tile = nxt;
    }
    #undef ISSUE_TILE

    // ---- flush histogram to global (device-scope atomics) ----
    #pragma unroll
    for (int i = tid; i < NCLASS; i += TROWS) {
        unsigned int c = lhist[i];
        if (c) atomicAdd(&counts[i], c);
    }

    // ---- last-block-done: one block computes the entropy ----
    __threadfence();                          // counts-atomics visible before done++
    if (tid == 0) {
        unsigned int prev = atomicAdd(done, 1u);
        s_last = (prev == gridDim.x - 1) ? 1u : 0u;
    }
    __syncthreads();

    if (s_last) {
        const float invB = 1.0f / (float)nrows;
        float term = 0.0f;
        #pragma unroll
        for (int i = tid; i < NCLASS; i += TROWS) {
            unsigned int c = atomicAdd(&counts[i], 0u);   // coherent read
            if (c) {
                float p = (float)c * invB;
                term += p * (logf(p) * 1.4426950408889634f);  // p * log2(p)
            }
        }
        // 64-lane shuffle reduce
        #pragma unroll
        for (int s = 32; s > 0; s >>= 1)
            term += __shfl_down(term, s, 64);
        if (tid == 0) out[0] = -term;
    }
}

extern "C" void kernel_launch(void* const* d_in, const int* in_sizes, int n_in,
                              void* d_out, int out_size, void* d_ws, size_t ws_size,
                              hipStream_t stream)
{
    const float* logits = (const float*)d_in[0];
    const int nrows = in_sizes[0] / NCLASS;

    unsigned int* counts = (unsigned int*)d_ws;        // [100]
    unsigned int* done   = counts + NCLASS;            // [1]
    (void)hipMemsetAsync(counts, 0, (NCLASS + 1) * sizeof(unsigned int), stream);

    const int grid = 768;   // 3 blocks/CU (LDS-capped), ~85 tiles per block
    argmax_hist_entropy_kernel<<<grid, TROWS, 0, stream>>>(
        (const fx4*)logits, counts, done, (float*)d_out, nrows);
}

// Round 9
// 288.128 us; speedup vs baseline: 1.0957x; 1.0957x over previous
//
#include <hip/hip_runtime.h>

#define NCLASS 100
#define TROWS 64       // rows per tile == threads per block (1 wave)
#define CHUNKS 25      // float4 chunks per row

typedef float fx4 __attribute__((ext_vector_type(4)));

// Double-buffered global_load_lds streaming (no VGPR staging, no barriers)
// + fused entropy epilogue. Release/acquire is done purely with device-scope
// atomics + s_waitcnt vmcnt(0): NO __threadfence(), whose buffer_wbl2/inv
// L2-walk per block cost ~30us in R8.
__global__ __launch_bounds__(64) void argmax_hist_entropy_kernel(
    const fx4* __restrict__ g4,
    unsigned int* __restrict__ counts,   // [NCLASS] zeroed by memset
    unsigned int* __restrict__ done,     // [1] zeroed by memset
    float* __restrict__ out,
    int nrows)
{
    __shared__ fx4 buf[2][CHUNKS * TROWS];   // 2 x 25600 B
    __shared__ unsigned int lhist[NCLASS];   // 400 B  -> 51.6 KB, 3 blocks/CU
    __shared__ unsigned int s_last;

    const int tid = threadIdx.x;
    #pragma unroll
    for (int i = tid; i < NCLASS; i += TROWS) lhist[i] = 0u;
    __syncthreads();

    const int ntiles = nrows / TROWS;        // 65536 exactly
    const int stride = gridDim.x;

    #define ISSUE_TILE(b_, tile_)                                               \
        {                                                                       \
            const fx4* src = g4 + (size_t)(tile_) * (CHUNKS * TROWS) + tid;     \
            _Pragma("unroll")                                                   \
            for (int i = 0; i < CHUNKS; ++i) {                                  \
                __builtin_amdgcn_global_load_lds(                               \
                    (const __attribute__((address_space(1))) void*)(src + i * TROWS), \
                    (__attribute__((address_space(3))) void*)(&buf[(b_)][i * TROWS]), \
                    16, 0, 0);                                                  \
            }                                                                   \
        }

    int tile = blockIdx.x;
    int b = 0;
    if (tile < ntiles) ISSUE_TILE(0, tile);

    while (tile < ntiles) {
        const int nxt = tile + stride;
        if (nxt < ntiles) {
            ISSUE_TILE(b ^ 1, nxt);
            // 50 outstanding; wait until <=25 -> buf[b]'s 25 have landed.
            asm volatile("s_waitcnt vmcnt(25)" ::: "memory");
        } else {
            asm volatile("s_waitcnt vmcnt(0)" ::: "memory");
        }
        __builtin_amdgcn_sched_barrier(0);   // keep reads below the wait

        // ---- row-scan: thread t reads row t (25 fx4) in column order ----
        const fx4* rp = &buf[b][tid * CHUNKS];   // row-major [64][100] floats
        float best = -__builtin_huge_valf();
        int bcol = 0;
        #pragma unroll
        for (int j = 0; j < CHUNKS; ++j) {
            const fx4 v = rp[j];
            if (v.x > best) { best = v.x; bcol = 4 * j + 0; }  // strict > => first max
            if (v.y > best) { best = v.y; bcol = 4 * j + 1; }
            if (v.z > best) { best = v.z; bcol = 4 * j + 2; }
            if (v.w > best) { best = v.w; bcol = 4 * j + 3; }
        }
        atomicAdd(&lhist[bcol], 1u);

        b ^= 1;
        tile = nxt;
    }
    #undef ISSUE_TILE

    // ---- flush histogram to global (device-scope atomics at L3 coherence pt) ----
    #pragma unroll
    for (int i = tid; i < NCLASS; i += TROWS) {
        unsigned int c = lhist[i];
        if (c) atomicAdd(&counts[i], c);
    }

    // ---- release: wait flush atomics complete (single wave), then done++ ----
    asm volatile("s_waitcnt vmcnt(0)" ::: "memory");   // no L2 wb/inv, unlike __threadfence
    if (tid == 0) {
        unsigned int prev = atomicAdd(done, 1u);
        s_last = (prev == gridDim.x - 1) ? 1u : 0u;
    }
    __syncthreads();

    // ---- last block computes entropy from the coherent counts ----
    if (s_last) {
        const float invB = 1.0f / (float)nrows;
        float term = 0.0f;
        #pragma unroll
        for (int i = tid; i < NCLASS; i += TROWS) {
            unsigned int c = atomicAdd(&counts[i], 0u);   // RMW read at coherence point
            if (c) {
                float p = (float)c * invB;
                term += p * (logf(p) * 1.4426950408889634f);  // p * log2(p)
            }
        }
        #pragma unroll
        for (int s = 32; s > 0; s >>= 1)
            term += __shfl_down(term, s, 64);
        if (tid == 0) out[0] = -term;
    }
}

extern "C" void kernel_launch(void* const* d_in, const int* in_sizes, int n_in,
                              void* d_out, int out_size, void* d_ws, size_t ws_size,
                              hipStream_t stream)
{
    const float* logits = (const float*)d_in[0];
    const int nrows = in_sizes[0] / NCLASS;

    unsigned int* counts = (unsigned int*)d_ws;        // [100]
    unsigned int* done   = counts + NCLASS;            // [1]
    (void)hipMemsetAsync(counts, 0, (NCLASS + 1) * sizeof(unsigned int), stream);

    const int grid = 768;   // 3 blocks/CU (LDS-capped), ~85 tiles per block
    argmax_hist_entropy_kernel<<<grid, TROWS, 0, stream>>>(
        (const fx4*)logits, counts, done, (float*)d_out, nrows);
}